// Round 2
// baseline (2151.794 us; speedup 1.0000x reference)
//
#include <hip/hip_runtime.h>
#include <math.h>

#define N_NODES 100000
#define N_EDGES 1600000
#define N_GRAPH 1000
#define IN_C 32
#define EDGE_C 16
#define DESC_C 200
#define HDIM 64
#define LAYERS 3

// K3[l][k][o] = sum_j edge_W[k][j] * emW1[l][64+j][o]   (rank-16 folding of ea @ W1_lower)
// kb3[l][o]  = sum_j edge_b[j] * emW1[l][64+j][o] + emb1[l][o]
__global__ void precompute_kernel(const float* __restrict__ edge_W, const float* __restrict__ edge_b,
                                  const float* __restrict__ emW1, const float* __restrict__ emb1,
                                  float* __restrict__ K3, float* __restrict__ kb3)
{
    int tid = blockIdx.x * blockDim.x + threadIdx.x;
    if (tid < LAYERS * EDGE_C * HDIM) {
        int l = tid / (EDGE_C * HDIM);
        int k = (tid / HDIM) % EDGE_C;
        int o = tid % HDIM;
        const float* W1l = emW1 + l * (2 * HDIM * HDIM) + HDIM * HDIM; // rows 64..127
        float acc = 0.f;
        for (int j = 0; j < HDIM; ++j)
            acc = fmaf(edge_W[k * HDIM + j], W1l[j * HDIM + o], acc);
        K3[tid] = acc;
    }
    if (tid < LAYERS * HDIM) {
        int l = tid / HDIM, o = tid % HDIM;
        const float* W1l = emW1 + l * (2 * HDIM * HDIM) + HDIM * HDIM;
        float acc = emb1[tid];
        for (int j = 0; j < HDIM; ++j)
            acc = fmaf(edge_b[j], W1l[j * HDIM + o], acc);
        kb3[tid] = acc;
    }
}

// h[n][o] = x[n] @ node_W + node_b
__global__ void node_embed_kernel(const float* __restrict__ x, const float* __restrict__ W,
                                  const float* __restrict__ b, float* __restrict__ h)
{
    __shared__ float sW[IN_C * HDIM];
    for (int i = threadIdx.x; i < IN_C * HDIM; i += blockDim.x) sW[i] = W[i];
    __syncthreads();
    int o = threadIdx.x & 63;
    int lw = threadIdx.x >> 6;
    float bias = b[o];
    for (int base = blockIdx.x * 4; base < N_NODES; base += gridDim.x * 4) {
        int n = base + lw;
        if (n < N_NODES) {
            const float* xr = x + (size_t)n * IN_C;
            float acc = bias;
            #pragma unroll
            for (int k = 0; k < IN_C; ++k) acc = fmaf(xr[k], sW[k * HDIM + o], acc);
            h[(size_t)n * HDIM + o] = acc;
        }
    }
}

// generic out[n][o] = in[n] @ W(64x64) (+ bias)
__global__ void linear64_kernel(const float* __restrict__ in, const float* __restrict__ W,
                                const float* __restrict__ b, float* __restrict__ out)
{
    __shared__ float sW[HDIM * HDIM];
    for (int i = threadIdx.x; i < HDIM * HDIM; i += blockDim.x) sW[i] = W[i];
    __syncthreads();
    int o = threadIdx.x & 63;
    int lw = threadIdx.x >> 6;
    float bias = b ? b[o] : 0.f;
    for (int base = blockIdx.x * 4; base < N_NODES; base += gridDim.x * 4) {
        int n = base + lw;
        if (n < N_NODES) {
            const float* ir = in + (size_t)n * HDIM;
            float acc = bias;
            #pragma unroll 16
            for (int k = 0; k < HDIM; ++k) acc = fmaf(ir[k], sW[k * HDIM + o], acc);
            out[(size_t)n * HDIM + o] = acc;
        }
    }
}

__global__ void deg_kernel(const int* __restrict__ ei, int* __restrict__ deg)
{
    int e = blockIdx.x * blockDim.x + threadIdx.x;
    if (e < N_EDGES) atomicAdd(&deg[ei[N_EDGES + e]], 1);
}

__global__ void cnt_kernel(const int* __restrict__ batch, int* __restrict__ cnt)
{
    int n = blockIdx.x * blockDim.x + threadIdx.x;
    if (n < N_NODES) atomicAdd(&cnt[batch[n]], 1);
}

// per edge: z = hW1[src] + edge_attr[e] @ K + kb ; aggZ[dst] += relu(z)
__global__ void edge_kernel(const int* __restrict__ ei, const float* __restrict__ ea,
                            const float* __restrict__ hW, const float* __restrict__ K,
                            const float* __restrict__ kb, float* __restrict__ aggZ)
{
    int o = threadIdx.x & 63;
    float Kr[EDGE_C];
    #pragma unroll
    for (int k = 0; k < EDGE_C; ++k) Kr[k] = K[k * HDIM + o];
    float kbo = kb[o];
    int wpb = blockDim.x >> 6;
    int wid = blockIdx.x * wpb + (threadIdx.x >> 6);
    int nw = gridDim.x * wpb;
    for (int e = wid; e < N_EDGES; e += nw) {
        int es = __builtin_amdgcn_readfirstlane(e);
        int src = ei[es];
        int dst = ei[N_EDGES + es];
        float z = hW[src * HDIM + o] + kbo;
        const float* ear = ea + (size_t)es * EDGE_C;
        #pragma unroll
        for (int k = 0; k < EDGE_C; ++k) z = fmaf(ear[k], Kr[k], z);
        z = fmaxf(z, 0.f);
        atomicAdd(&aggZ[dst * HDIM + o], z);
    }
}

// t1 = relu( h @ umW1[:64] + (aggZ @ emW2 + deg*emb2) @ umW1[64:] + umb1 )
__global__ void update1_kernel(const float* __restrict__ h, const float* __restrict__ aggZ,
                               const int* __restrict__ deg,
                               const float* __restrict__ emW2, const float* __restrict__ emb2,
                               const float* __restrict__ umW1, const float* __restrict__ umb1,
                               float* __restrict__ t1)
{
    __shared__ float sW2[HDIM * HDIM];      // 16 KB
    __shared__ float sU1[2 * HDIM * HDIM];  // 32 KB
    __shared__ float sZ[4][HDIM];
    __shared__ float sA[4][HDIM];
    __shared__ float sH[4][HDIM];
    for (int i = threadIdx.x; i < HDIM * HDIM; i += blockDim.x) sW2[i] = emW2[i];
    for (int i = threadIdx.x; i < 2 * HDIM * HDIM; i += blockDim.x) sU1[i] = umW1[i];
    __syncthreads();
    int o = threadIdx.x & 63;
    int lw = threadIdx.x >> 6;
    float eb2 = emb2[o], ub1 = umb1[o];
    for (int base = blockIdx.x * 4; base < N_NODES; base += gridDim.x * 4) {
        int n = base + lw;
        bool valid = n < N_NODES;
        float zr = valid ? aggZ[(size_t)n * HDIM + o] : 0.f;
        float hr = valid ? h[(size_t)n * HDIM + o] : 0.f;
        float dg = valid ? (float)deg[n] : 0.f;
        sZ[lw][o] = zr;
        sH[lw][o] = hr;
        float agg = dg * eb2;
        #pragma unroll 16
        for (int k = 0; k < HDIM; ++k) agg = fmaf(sZ[lw][k], sW2[k * HDIM + o], agg);
        sA[lw][o] = agg;
        float t = ub1;
        #pragma unroll 16
        for (int k = 0; k < HDIM; ++k) t = fmaf(sH[lw][k], sU1[k * HDIM + o], t);
        #pragma unroll 16
        for (int k = 0; k < HDIM; ++k) t = fmaf(sA[lw][k], sU1[(HDIM + k) * HDIM + o], t);
        t = fmaxf(t, 0.f);
        if (valid) t1[(size_t)n * HDIM + o] = t;
    }
}

__global__ void pool_kernel(const float* __restrict__ h, const int* __restrict__ batch,
                            float* __restrict__ pooled)
{
    int idx = blockIdx.x * blockDim.x + threadIdx.x;
    if (idx < N_NODES * HDIM) {
        int n = idx >> 6, o = idx & 63;
        int g = batch[n];
        atomicAdd(&pooled[g * HDIM + o], h[idx]);
    }
}

__global__ void readout_kernel(const float* __restrict__ pooled, const int* __restrict__ cnt,
                               const float* __restrict__ desc,
                               const float* __restrict__ W1, const float* __restrict__ b1,
                               const float* __restrict__ W2, const float* __restrict__ b2,
                               float* __restrict__ out)
{
    __shared__ float r[HDIM + DESC_C];
    __shared__ float red[128];
    int g = blockIdx.x;
    int t = threadIdx.x;
    float c = fmaxf((float)cnt[g], 1.f);
    for (int i = t; i < HDIM; i += 128) r[i] = pooled[g * HDIM + i] / c;
    for (int i = t; i < DESC_C; i += 128) r[HDIM + i] = desc[(size_t)g * DESC_C + i];
    __syncthreads();
    float acc = b1[t];
    for (int k = 0; k < HDIM + DESC_C; ++k) acc = fmaf(r[k], W1[k * 128 + t], acc);
    acc = fmaxf(acc, 0.f) * W2[t];
    red[t] = acc;
    __syncthreads();
    for (int s = 64; s > 0; s >>= 1) {
        if (t < s) red[t] += red[t + s];
        __syncthreads();
    }
    if (t == 0) out[g] = 1.f / (1.f + expf(-(red[0] + b2[0])));
}

extern "C" void kernel_launch(void* const* d_in, const int* in_sizes, int n_in,
                              void* d_out, int out_size, void* d_ws, size_t ws_size,
                              hipStream_t stream)
{
    const float* x         = (const float*)d_in[0];
    const int*   ei        = (const int*)d_in[1];
    const float* edge_attr = (const float*)d_in[2];
    const int*   batch     = (const int*)d_in[3];
    const float* desc      = (const float*)d_in[4];
    const float* node_W    = (const float*)d_in[5];
    const float* node_b    = (const float*)d_in[6];
    const float* edge_W    = (const float*)d_in[7];
    const float* edge_b    = (const float*)d_in[8];
    const float* emW1      = (const float*)d_in[9];
    const float* emb1      = (const float*)d_in[10];
    const float* emW2      = (const float*)d_in[11];
    const float* emb2      = (const float*)d_in[12];
    const float* umW1      = (const float*)d_in[13];
    const float* umb1      = (const float*)d_in[14];
    const float* umW2      = (const float*)d_in[15];
    const float* umb2      = (const float*)d_in[16];
    const float* ro_W1     = (const float*)d_in[17];
    const float* ro_b1     = (const float*)d_in[18];
    const float* ro_W2     = (const float*)d_in[19];
    const float* ro_b2     = (const float*)d_in[20];

    size_t NH = (size_t)N_NODES * HDIM;
    float* bufA = (float*)d_ws;          // h (persistent across layers)
    float* bufB = bufA + NH;             // hW1 / t1 scratch
    float* bufC = bufB + NH;             // aggZ
    int*   deg  = (int*)(bufC + NH);
    float* K3   = (float*)(deg + N_NODES);
    float* kb3  = K3 + LAYERS * EDGE_C * HDIM;
    float* pooled = kb3 + LAYERS * HDIM;
    int*   cnt  = (int*)(pooled + N_GRAPH * HDIM);

    hipMemsetAsync(deg, 0, N_NODES * sizeof(int), stream);
    hipMemsetAsync(pooled, 0, N_GRAPH * HDIM * sizeof(float), stream);
    hipMemsetAsync(cnt, 0, N_GRAPH * sizeof(int), stream);

    precompute_kernel<<<12, 256, 0, stream>>>(edge_W, edge_b, emW1, emb1, K3, kb3);
    node_embed_kernel<<<2048, 256, 0, stream>>>(x, node_W, node_b, bufA);
    deg_kernel<<<(N_EDGES + 255) / 256, 256, 0, stream>>>(ei, deg);
    cnt_kernel<<<(N_NODES + 255) / 256, 256, 0, stream>>>(batch, cnt);

    for (int l = 0; l < LAYERS; ++l) {
        // hW1 = h @ emW1_upper   (bufA -> bufB)
        linear64_kernel<<<2048, 256, 0, stream>>>(bufA, emW1 + l * 2 * HDIM * HDIM, nullptr, bufB);
        hipMemsetAsync(bufC, 0, NH * sizeof(float), stream);
        // aggZ = scatter-add relu(hW1[src] + ea@K + kb)   (bufB -> bufC)
        edge_kernel<<<4096, 256, 0, stream>>>(ei, edge_attr, bufB,
                                              K3 + l * EDGE_C * HDIM, kb3 + l * HDIM, bufC);
        // t1 = relu(h@umW1u + (aggZ@emW2 + deg*emb2)@umW1l + umb1)   ((bufA,bufC) -> bufB)
        update1_kernel<<<2048, 256, 0, stream>>>(bufA, bufC, deg,
                                                 emW2 + l * HDIM * HDIM, emb2 + l * HDIM,
                                                 umW1 + l * 2 * HDIM * HDIM, umb1 + l * HDIM, bufB);
        // h = t1 @ umW2 + umb2   (bufB -> bufA)
        linear64_kernel<<<2048, 256, 0, stream>>>(bufB, umW2 + l * HDIM * HDIM, umb2 + l * HDIM, bufA);
    }

    pool_kernel<<<(N_NODES * HDIM + 255) / 256, 256, 0, stream>>>(bufA, batch, pooled);
    readout_kernel<<<N_GRAPH, 128, 0, stream>>>(pooled, cnt, desc, ro_W1, ro_b1, ro_W2, ro_b2,
                                                (float*)d_out);
}

// Round 3
// 1412.402 us; speedup vs baseline: 1.5235x; 1.5235x over previous
//
#include <hip/hip_runtime.h>
#include <math.h>

#define N_NODES 100000
#define N_EDGES 1600000
#define N_GRAPH 1000
#define IN_C 32
#define EDGE_C 16
#define DESC_C 200
#define HDIM 64
#define LAYERS 3
#define SCAN_B 1024
#define N_SBLK ((N_NODES + SCAN_B - 1) / SCAN_B)   // 98

// ---------------- weight folding (once) ----------------
// K3[l][k][o] = sum_j edge_W[k][j] * emW1[l][64+j][o]
// kb3[l][o]  = sum_j edge_b[j] * emW1[l][64+j][o] + emb1[l][o]
__global__ void precompute_kernel(const float* __restrict__ edge_W, const float* __restrict__ edge_b,
                                  const float* __restrict__ emW1, const float* __restrict__ emb1,
                                  float* __restrict__ K3, float* __restrict__ kb3)
{
    int tid = blockIdx.x * blockDim.x + threadIdx.x;
    if (tid < LAYERS * EDGE_C * HDIM) {
        int l = tid / (EDGE_C * HDIM);
        int k = (tid / HDIM) % EDGE_C;
        int o = tid % HDIM;
        const float* W1l = emW1 + l * (2 * HDIM * HDIM) + HDIM * HDIM;
        float acc = 0.f;
        for (int j = 0; j < HDIM; ++j)
            acc = fmaf(edge_W[k * HDIM + j], W1l[j * HDIM + o], acc);
        K3[tid] = acc;
    }
    if (tid < LAYERS * HDIM) {
        int l = tid / HDIM, o = tid % HDIM;
        const float* W1l = emW1 + l * (2 * HDIM * HDIM) + HDIM * HDIM;
        float acc = emb1[tid];
        for (int j = 0; j < HDIM; ++j)
            acc = fmaf(edge_b[j], W1l[j * HDIM + o], acc);
        kb3[tid] = acc;
    }
}

// ---------------- CSR build ----------------
__global__ void deg_kernel(const int* __restrict__ ei, int* __restrict__ deg)
{
    int e = blockIdx.x * blockDim.x + threadIdx.x;
    if (e < N_EDGES) atomicAdd(&deg[ei[N_EDGES + e]], 1);
}

__global__ void cnt_kernel(const int* __restrict__ batch, int* __restrict__ cnt)
{
    int n = blockIdx.x * blockDim.x + threadIdx.x;
    if (n < N_NODES) atomicAdd(&cnt[batch[n]], 1);
}

// per-block exclusive scan; writes block totals
__global__ void scanA_kernel(const int* __restrict__ in, int* __restrict__ out, int* __restrict__ bsum)
{
    __shared__ int s[SCAN_B];
    int gid = blockIdx.x * SCAN_B + threadIdx.x;
    int v = (gid < N_NODES) ? in[gid] : 0;
    s[threadIdx.x] = v;
    __syncthreads();
    for (int off = 1; off < SCAN_B; off <<= 1) {
        int t = (threadIdx.x >= off) ? s[threadIdx.x - off] : 0;
        __syncthreads();
        s[threadIdx.x] += t;
        __syncthreads();
    }
    if (gid < N_NODES) out[gid] = s[threadIdx.x] - v;   // exclusive
    if (threadIdx.x == SCAN_B - 1) bsum[blockIdx.x] = s[SCAN_B - 1];
}

// single-block exclusive scan of n<=1024 elements, out[n]=total
__global__ void scan1b_kernel(const int* __restrict__ in, int n, int* __restrict__ out)
{
    __shared__ int s[SCAN_B];
    int v = (threadIdx.x < n) ? in[threadIdx.x] : 0;
    s[threadIdx.x] = v;
    __syncthreads();
    for (int off = 1; off < SCAN_B; off <<= 1) {
        int t = (threadIdx.x >= off) ? s[threadIdx.x - off] : 0;
        __syncthreads();
        s[threadIdx.x] += t;
        __syncthreads();
    }
    if (threadIdx.x < n) out[threadIdx.x] = s[threadIdx.x] - v;
    if (threadIdx.x == 0) out[n] = s[SCAN_B - 1];
}

__global__ void scanC_kernel(int* __restrict__ rowptr, const int* __restrict__ bscan,
                             int* __restrict__ cursor)
{
    int gid = blockIdx.x * SCAN_B + threadIdx.x;
    if (gid < N_NODES) {
        int r = rowptr[gid] + bscan[blockIdx.x];
        rowptr[gid] = r;
        cursor[gid] = r;
    }
    if (gid == 0) rowptr[N_NODES] = N_EDGES;
}

__global__ void fill_kernel(const int* __restrict__ ei, int* __restrict__ cursor,
                            int2* __restrict__ srcE)
{
    int e = blockIdx.x * blockDim.x + threadIdx.x;
    if (e < N_EDGES) {
        int src = ei[e];
        int dst = ei[N_EDGES + e];
        int pos = atomicAdd(&cursor[dst], 1);
        srcE[pos] = make_int2(src, e);
    }
}

// ---------------- node embed: h = x @ node_W + node_b  (K=32) ----------------
__global__ void lin32_kernel(const float* __restrict__ in, const float* __restrict__ W,
                             const float* __restrict__ b, float* __restrict__ out)
{
    int o = threadIdx.x & 63;
    int w = threadIdx.x >> 6;
    float Wc[IN_C];
    #pragma unroll
    for (int k = 0; k < IN_C; ++k) Wc[k] = W[k * HDIM + o];
    float bias = b[o];
    __shared__ float srow[4][IN_C];
    int wid = blockIdx.x * 4 + w, nw = gridDim.x * 4;
    for (int n = wid; n < N_NODES; n += nw) {
        srow[w][o & 31] = in[(size_t)n * IN_C + (o & 31)];
        float acc = bias;
        #pragma unroll
        for (int k4 = 0; k4 < IN_C / 4; ++k4) {
            float4 c = *reinterpret_cast<const float4*>(&srow[w][k4 * 4]);
            acc = fmaf(c.x, Wc[4 * k4 + 0], acc);
            acc = fmaf(c.y, Wc[4 * k4 + 1], acc);
            acc = fmaf(c.z, Wc[4 * k4 + 2], acc);
            acc = fmaf(c.w, Wc[4 * k4 + 3], acc);
        }
        out[(size_t)n * HDIM + o] = acc;
    }
}

// ---------------- 64x64 linear: out = act(in @ W + b [+ deg*dbias]) ----------------
__global__ void lin64_kernel(const float* __restrict__ in, const float* __restrict__ W,
                             const float* __restrict__ b, const int* __restrict__ deg,
                             const float* __restrict__ dbias, int relu, float* __restrict__ out)
{
    int o = threadIdx.x & 63;
    int w = threadIdx.x >> 6;
    float Wc[HDIM];
    #pragma unroll
    for (int k = 0; k < HDIM; ++k) Wc[k] = W[k * HDIM + o];
    float bias = b ? b[o] : 0.f;
    float db = dbias ? dbias[o] : 0.f;
    __shared__ float srow[4][HDIM];
    int wid = blockIdx.x * 4 + w, nw = gridDim.x * 4;
    for (int n = wid; n < N_NODES; n += nw) {
        srow[w][o] = in[(size_t)n * HDIM + o];
        float acc = bias;
        if (deg) acc = fmaf((float)deg[n], db, acc);
        #pragma unroll
        for (int k4 = 0; k4 < HDIM / 4; ++k4) {
            float4 c = *reinterpret_cast<const float4*>(&srow[w][k4 * 4]);
            acc = fmaf(c.x, Wc[4 * k4 + 0], acc);
            acc = fmaf(c.y, Wc[4 * k4 + 1], acc);
            acc = fmaf(c.z, Wc[4 * k4 + 2], acc);
            acc = fmaf(c.w, Wc[4 * k4 + 3], acc);
        }
        if (relu) acc = fmaxf(acc, 0.f);
        out[(size_t)n * HDIM + o] = acc;
    }
}

// out = relu(in1 @ W1 + in2 @ W2 + b)
__global__ void lin64_dual_kernel(const float* __restrict__ in1, const float* __restrict__ W1,
                                  const float* __restrict__ in2, const float* __restrict__ W2,
                                  const float* __restrict__ b, float* __restrict__ out)
{
    int o = threadIdx.x & 63;
    int w = threadIdx.x >> 6;
    float Wc1[HDIM], Wc2[HDIM];
    #pragma unroll
    for (int k = 0; k < HDIM; ++k) Wc1[k] = W1[k * HDIM + o];
    #pragma unroll
    for (int k = 0; k < HDIM; ++k) Wc2[k] = W2[k * HDIM + o];
    float bias = b[o];
    __shared__ float srA[4][HDIM];
    __shared__ float srB[4][HDIM];
    int wid = blockIdx.x * 4 + w, nw = gridDim.x * 4;
    for (int n = wid; n < N_NODES; n += nw) {
        srA[w][o] = in1[(size_t)n * HDIM + o];
        srB[w][o] = in2[(size_t)n * HDIM + o];
        float acc = bias;
        #pragma unroll
        for (int k4 = 0; k4 < HDIM / 4; ++k4) {
            float4 c = *reinterpret_cast<const float4*>(&srA[w][k4 * 4]);
            acc = fmaf(c.x, Wc1[4 * k4 + 0], acc);
            acc = fmaf(c.y, Wc1[4 * k4 + 1], acc);
            acc = fmaf(c.z, Wc1[4 * k4 + 2], acc);
            acc = fmaf(c.w, Wc1[4 * k4 + 3], acc);
        }
        #pragma unroll
        for (int k4 = 0; k4 < HDIM / 4; ++k4) {
            float4 c = *reinterpret_cast<const float4*>(&srB[w][k4 * 4]);
            acc = fmaf(c.x, Wc2[4 * k4 + 0], acc);
            acc = fmaf(c.y, Wc2[4 * k4 + 1], acc);
            acc = fmaf(c.z, Wc2[4 * k4 + 2], acc);
            acc = fmaf(c.w, Wc2[4 * k4 + 3], acc);
        }
        out[(size_t)n * HDIM + o] = fmaxf(acc, 0.f);
    }
}

// ---------------- edge aggregation (CSR gather, no atomics) ----------------
__device__ __forceinline__ float edge_z(const float* hWrow, int o, const float4* er,
                                        const float* Kc, float kbo)
{
    float z = hWrow[o] + kbo;
    float4 e0 = er[0], e1 = er[1], e2 = er[2], e3 = er[3];
    z = fmaf(e0.x, Kc[0], z);  z = fmaf(e0.y, Kc[1], z);
    z = fmaf(e0.z, Kc[2], z);  z = fmaf(e0.w, Kc[3], z);
    z = fmaf(e1.x, Kc[4], z);  z = fmaf(e1.y, Kc[5], z);
    z = fmaf(e1.z, Kc[6], z);  z = fmaf(e1.w, Kc[7], z);
    z = fmaf(e2.x, Kc[8], z);  z = fmaf(e2.y, Kc[9], z);
    z = fmaf(e2.z, Kc[10], z); z = fmaf(e2.w, Kc[11], z);
    z = fmaf(e3.x, Kc[12], z); z = fmaf(e3.y, Kc[13], z);
    z = fmaf(e3.z, Kc[14], z); z = fmaf(e3.w, Kc[15], z);
    return fmaxf(z, 0.f);
}

__global__ void edge_agg_kernel(const int* __restrict__ rowptr, const int2* __restrict__ srcE,
                                const float* __restrict__ ea, const float* __restrict__ hW,
                                const float* __restrict__ K, const float* __restrict__ kb,
                                float* __restrict__ aggZ)
{
    int o = threadIdx.x & 63;
    int w = threadIdx.x >> 6;
    float Kc[EDGE_C];
    #pragma unroll
    for (int k = 0; k < EDGE_C; ++k) Kc[k] = K[k * HDIM + o];
    float kbo = kb[o];
    int wid = blockIdx.x * 4 + w, nw = gridDim.x * 4;
    for (int n = wid; n < N_NODES; n += nw) {
        int beg = __builtin_amdgcn_readfirstlane(rowptr[n]);
        int end = __builtin_amdgcn_readfirstlane(rowptr[n + 1]);
        float acc = 0.f;
        int p = beg;
        for (; p + 1 < end; p += 2) {
            int2 se0 = srcE[p], se1 = srcE[p + 1];
            const float* hr0 = hW + (size_t)se0.x * HDIM;
            const float* hr1 = hW + (size_t)se1.x * HDIM;
            const float4* er0 = (const float4*)(ea + (size_t)se0.y * EDGE_C);
            const float4* er1 = (const float4*)(ea + (size_t)se1.y * EDGE_C);
            acc += edge_z(hr0, o, er0, Kc, kbo);
            acc += edge_z(hr1, o, er1, Kc, kbo);
        }
        if (p < end) {
            int2 se = srcE[p];
            acc += edge_z(hW + (size_t)se.x * HDIM, o,
                          (const float4*)(ea + (size_t)se.y * EDGE_C), Kc, kbo);
        }
        aggZ[(size_t)n * HDIM + o] = acc;
    }
}

// ---------------- pooling (sorted batch -> wave per graph) ----------------
__global__ void pool_graph_kernel(const float* __restrict__ h, const int* __restrict__ gptr,
                                  float* __restrict__ pooled)
{
    int o = threadIdx.x & 63;
    int w = threadIdx.x >> 6;
    int wid = blockIdx.x * 4 + w, nw = gridDim.x * 4;
    for (int g = wid; g < N_GRAPH; g += nw) {
        int beg = gptr[g], end = gptr[g + 1];
        float acc = 0.f;
        for (int n = beg; n < end; ++n) acc += h[(size_t)n * HDIM + o];
        pooled[g * HDIM + o] = acc;
    }
}

__global__ void readout_kernel(const float* __restrict__ pooled, const int* __restrict__ cnt,
                               const float* __restrict__ desc,
                               const float* __restrict__ W1, const float* __restrict__ b1,
                               const float* __restrict__ W2, const float* __restrict__ b2,
                               float* __restrict__ out)
{
    __shared__ float r[HDIM + DESC_C];
    __shared__ float red[128];
    int g = blockIdx.x;
    int t = threadIdx.x;
    float c = fmaxf((float)cnt[g], 1.f);
    for (int i = t; i < HDIM; i += 128) r[i] = pooled[g * HDIM + i] / c;
    for (int i = t; i < DESC_C; i += 128) r[HDIM + i] = desc[(size_t)g * DESC_C + i];
    __syncthreads();
    float acc = b1[t];
    for (int k = 0; k < HDIM + DESC_C; ++k) acc = fmaf(r[k], W1[k * 128 + t], acc);
    acc = fmaxf(acc, 0.f) * W2[t];
    red[t] = acc;
    __syncthreads();
    for (int s = 64; s > 0; s >>= 1) {
        if (t < s) red[t] += red[t + s];
        __syncthreads();
    }
    if (t == 0) out[g] = 1.f / (1.f + expf(-(red[0] + b2[0])));
}

extern "C" void kernel_launch(void* const* d_in, const int* in_sizes, int n_in,
                              void* d_out, int out_size, void* d_ws, size_t ws_size,
                              hipStream_t stream)
{
    const float* x         = (const float*)d_in[0];
    const int*   ei        = (const int*)d_in[1];
    const float* edge_attr = (const float*)d_in[2];
    const int*   batch     = (const int*)d_in[3];
    const float* desc      = (const float*)d_in[4];
    const float* node_W    = (const float*)d_in[5];
    const float* node_b    = (const float*)d_in[6];
    const float* edge_W    = (const float*)d_in[7];
    const float* edge_b    = (const float*)d_in[8];
    const float* emW1      = (const float*)d_in[9];
    const float* emb1      = (const float*)d_in[10];
    const float* emW2      = (const float*)d_in[11];
    const float* emb2      = (const float*)d_in[12];
    const float* umW1      = (const float*)d_in[13];
    const float* umb1      = (const float*)d_in[14];
    const float* umW2      = (const float*)d_in[15];
    const float* umb2      = (const float*)d_in[16];
    const float* ro_W1     = (const float*)d_in[17];
    const float* ro_b1     = (const float*)d_in[18];
    const float* ro_W2     = (const float*)d_in[19];
    const float* ro_b2     = (const float*)d_in[20];

    size_t NH = (size_t)N_NODES * HDIM;
    float* bufA   = (float*)d_ws;          // h
    float* bufB   = bufA + NH;             // hW1 / A
    float* bufC   = bufB + NH;             // aggZ / t
    int2*  srcE   = (int2*)(bufC + NH);    // 8B aligned (NH even)
    int*   deg    = (int*)(srcE + N_EDGES);
    int*   rowptr = deg + N_NODES;
    int*   cursor = rowptr + N_NODES + 1;
    int*   cnt    = cursor + N_NODES;
    int*   gptr   = cnt + N_GRAPH;
    int*   bsum   = gptr + N_GRAPH + 1;
    int*   bscan  = bsum + N_SBLK;
    float* K3     = (float*)(bscan + N_SBLK + 1);
    float* kb3    = K3 + LAYERS * EDGE_C * HDIM;
    float* pooled = kb3 + LAYERS * HDIM;

    hipMemsetAsync(deg, 0, N_NODES * sizeof(int), stream);
    hipMemsetAsync(cnt, 0, N_GRAPH * sizeof(int), stream);

    precompute_kernel<<<12, 256, 0, stream>>>(edge_W, edge_b, emW1, emb1, K3, kb3);
    lin32_kernel<<<2048, 256, 0, stream>>>(x, node_W, node_b, bufA);
    deg_kernel<<<(N_EDGES + 255) / 256, 256, 0, stream>>>(ei, deg);
    cnt_kernel<<<(N_NODES + 255) / 256, 256, 0, stream>>>(batch, cnt);

    // CSR build
    scanA_kernel<<<N_SBLK, SCAN_B, 0, stream>>>(deg, rowptr, bsum);
    scan1b_kernel<<<1, SCAN_B, 0, stream>>>(bsum, N_SBLK, bscan);
    scanC_kernel<<<N_SBLK, SCAN_B, 0, stream>>>(rowptr, bscan, cursor);
    fill_kernel<<<(N_EDGES + 255) / 256, 256, 0, stream>>>(ei, cursor, srcE);

    // graph ptr for pooling
    scan1b_kernel<<<1, SCAN_B, 0, stream>>>(cnt, N_GRAPH, gptr);

    for (int l = 0; l < LAYERS; ++l) {
        const float* W1u = emW1 + l * 2 * HDIM * HDIM;           // rows 0..63
        // hW1 = h @ emW1_upper
        lin64_kernel<<<4096, 256, 0, stream>>>(bufA, W1u, nullptr, nullptr, nullptr, 0, bufB);
        // aggZ = sum_dst relu(hW1[src] + ea@K + kb)
        edge_agg_kernel<<<4096, 256, 0, stream>>>(rowptr, srcE, edge_attr, bufB,
                                                  K3 + l * EDGE_C * HDIM, kb3 + l * HDIM, bufC);
        // A = aggZ @ emW2 + deg*emb2
        lin64_kernel<<<4096, 256, 0, stream>>>(bufC, emW2 + l * HDIM * HDIM, nullptr,
                                               deg, emb2 + l * HDIM, 0, bufB);
        // t = relu(h @ umW1u + A @ umW1l + umb1)
        lin64_dual_kernel<<<4096, 256, 0, stream>>>(bufA, umW1 + l * 2 * HDIM * HDIM,
                                                    bufB, umW1 + l * 2 * HDIM * HDIM + HDIM * HDIM,
                                                    umb1 + l * HDIM, bufC);
        // h = t @ umW2 + umb2
        lin64_kernel<<<4096, 256, 0, stream>>>(bufC, umW2 + l * HDIM * HDIM, umb2 + l * HDIM,
                                               nullptr, nullptr, 0, bufA);
    }

    pool_graph_kernel<<<256, 256, 0, stream>>>(bufA, gptr, pooled);
    readout_kernel<<<N_GRAPH, 128, 0, stream>>>(pooled, cnt, desc, ro_W1, ro_b1, ro_W2, ro_b2,
                                                (float*)d_out);
}

// Round 5
// 1287.799 us; speedup vs baseline: 1.6709x; 1.0968x over previous
//
#include <hip/hip_runtime.h>
#include <hip/hip_fp16.h>
#include <math.h>

#define N_NODES 100000
#define N_EDGES 1600000
#define N_GRAPH 1000
#define IN_C 32
#define EDGE_C 16
#define DESC_C 200
#define HDIM 64
#define LAYERS 3
#define SCAN_B 1024
#define N_SBLK ((N_NODES + SCAN_B - 1) / SCAN_B)   // 98

// ---------------- helpers ----------------
__device__ __forceinline__ float2 h2f2(unsigned int u) {
    __half2 h = *reinterpret_cast<const __half2*>(&u);
    return __half22float2(h);
}
__device__ __forceinline__ unsigned int f2h2(float a, float b) {
    __half2 h = __floats2half2_rn(a, b);
    return *reinterpret_cast<unsigned int*>(&h);
}

// ---------------- weight folding (once) ----------------
__global__ void precompute_kernel(const float* __restrict__ edge_W, const float* __restrict__ edge_b,
                                  const float* __restrict__ emW1, const float* __restrict__ emb1,
                                  float* __restrict__ K3, float* __restrict__ kb3)
{
    int tid = blockIdx.x * blockDim.x + threadIdx.x;
    if (tid < LAYERS * EDGE_C * HDIM) {
        int l = tid / (EDGE_C * HDIM);
        int k = (tid / HDIM) % EDGE_C;
        int o = tid % HDIM;
        const float* W1l = emW1 + l * (2 * HDIM * HDIM) + HDIM * HDIM;
        float acc = 0.f;
        for (int j = 0; j < HDIM; ++j)
            acc = fmaf(edge_W[k * HDIM + j], W1l[j * HDIM + o], acc);
        K3[tid] = acc;
    }
    if (tid < LAYERS * HDIM) {
        int l = tid / HDIM, o = tid % HDIM;
        const float* W1l = emW1 + l * (2 * HDIM * HDIM) + HDIM * HDIM;
        float acc = emb1[tid];
        for (int j = 0; j < HDIM; ++j)
            acc = fmaf(edge_b[j], W1l[j * HDIM + o], acc);
        kb3[tid] = acc;
    }
}

// ---------------- CSR build ----------------
__global__ void deg_kernel(const int* __restrict__ ei, int* __restrict__ deg)
{
    int e = blockIdx.x * blockDim.x + threadIdx.x;
    if (e < N_EDGES) atomicAdd(&deg[ei[N_EDGES + e]], 1);
}

__global__ void cnt_kernel(const int* __restrict__ batch, int* __restrict__ cnt)
{
    int n = blockIdx.x * blockDim.x + threadIdx.x;
    if (n < N_NODES) atomicAdd(&cnt[batch[n]], 1);
}

__global__ void scanA_kernel(const int* __restrict__ in, int* __restrict__ out, int* __restrict__ bsum)
{
    __shared__ int s[SCAN_B];
    int gid = blockIdx.x * SCAN_B + threadIdx.x;
    int v = (gid < N_NODES) ? in[gid] : 0;
    s[threadIdx.x] = v;
    __syncthreads();
    for (int off = 1; off < SCAN_B; off <<= 1) {
        int t = (threadIdx.x >= off) ? s[threadIdx.x - off] : 0;
        __syncthreads();
        s[threadIdx.x] += t;
        __syncthreads();
    }
    if (gid < N_NODES) out[gid] = s[threadIdx.x] - v;
    if (threadIdx.x == SCAN_B - 1) bsum[blockIdx.x] = s[SCAN_B - 1];
}

__global__ void scan1b_kernel(const int* __restrict__ in, int n, int* __restrict__ out)
{
    __shared__ int s[SCAN_B];
    int v = (threadIdx.x < n) ? in[threadIdx.x] : 0;
    s[threadIdx.x] = v;
    __syncthreads();
    for (int off = 1; off < SCAN_B; off <<= 1) {
        int t = (threadIdx.x >= off) ? s[threadIdx.x - off] : 0;
        __syncthreads();
        s[threadIdx.x] += t;
        __syncthreads();
    }
    if (threadIdx.x < n) out[threadIdx.x] = s[threadIdx.x] - v;
    if (threadIdx.x == 0) out[n] = s[SCAN_B - 1];
}

__global__ void scanC_kernel(int* __restrict__ rowptr, const int* __restrict__ bscan,
                             int* __restrict__ cursor)
{
    int gid = blockIdx.x * SCAN_B + threadIdx.x;
    if (gid < N_NODES) {
        int r = rowptr[gid] + bscan[blockIdx.x];
        rowptr[gid] = r;
        cursor[gid] = r;
    }
    if (gid == 0) rowptr[N_NODES] = N_EDGES;
}

__global__ void fill_kernel(const int* __restrict__ ei, int* __restrict__ cursor,
                            int* __restrict__ srcIdx, int* __restrict__ eIdx)
{
    int e = blockIdx.x * blockDim.x + threadIdx.x;
    if (e < N_EDGES) {
        int src = ei[e];
        int dst = ei[N_EDGES + e];
        int pos = atomicAdd(&cursor[dst], 1);
        srcIdx[pos] = src;
        eIdx[pos] = e;
    }
}

// permute edge_attr into CSR order as fp16 (gather-read, streaming-write)
__global__ void perm_kernel(const int* __restrict__ eIdx, const float* __restrict__ ea,
                            uint4* __restrict__ eaPh)
{
    int pos = blockIdx.x * blockDim.x + threadIdx.x;
    if (pos < N_EDGES) {
        int e = eIdx[pos];
        const float4* er = reinterpret_cast<const float4*>(ea + (size_t)e * EDGE_C);
        float4 f0 = er[0], f1 = er[1], f2 = er[2], f3 = er[3];
        uint4 u0, u1;
        u0.x = f2h2(f0.x, f0.y);  u0.y = f2h2(f0.z, f0.w);
        u0.z = f2h2(f1.x, f1.y);  u0.w = f2h2(f1.z, f1.w);
        u1.x = f2h2(f2.x, f2.y);  u1.y = f2h2(f2.z, f2.w);
        u1.z = f2h2(f3.x, f3.y);  u1.w = f2h2(f3.z, f3.w);
        eaPh[2 * (size_t)pos]     = u0;
        eaPh[2 * (size_t)pos + 1] = u1;
    }
}

// ---------------- node embed: h = x @ node_W + node_b  (K=32) ----------------
__global__ void lin32_kernel(const float* __restrict__ in, const float* __restrict__ W,
                             const float* __restrict__ b, float* __restrict__ out)
{
    int o = threadIdx.x & 63;
    int w = threadIdx.x >> 6;
    float Wc[IN_C];
    #pragma unroll
    for (int k = 0; k < IN_C; ++k) Wc[k] = W[k * HDIM + o];
    float bias = b[o];
    __shared__ float srow[4][IN_C];
    int wid = blockIdx.x * 4 + w, nw = gridDim.x * 4;
    for (int n = wid; n < N_NODES; n += nw) {
        srow[w][o & 31] = in[(size_t)n * IN_C + (o & 31)];
        float acc = bias;
        #pragma unroll
        for (int k4 = 0; k4 < IN_C / 4; ++k4) {
            float4 c = *reinterpret_cast<const float4*>(&srow[w][k4 * 4]);
            acc = fmaf(c.x, Wc[4 * k4 + 0], acc);
            acc = fmaf(c.y, Wc[4 * k4 + 1], acc);
            acc = fmaf(c.z, Wc[4 * k4 + 2], acc);
            acc = fmaf(c.w, Wc[4 * k4 + 3], acc);
        }
        out[(size_t)n * HDIM + o] = acc;
    }
}

// ---------------- 64x64 linear: out = act(in @ W + b [+ deg*dbias]) ----------------
__global__ void lin64_kernel(const float* __restrict__ in, const float* __restrict__ W,
                             const float* __restrict__ b, const int* __restrict__ deg,
                             const float* __restrict__ dbias, int relu,
                             float* __restrict__ out, __half* __restrict__ outH)
{
    int o = threadIdx.x & 63;
    int w = threadIdx.x >> 6;
    float Wc[HDIM];
    #pragma unroll
    for (int k = 0; k < HDIM; ++k) Wc[k] = W[k * HDIM + o];
    float bias = b ? b[o] : 0.f;
    float db = dbias ? dbias[o] : 0.f;
    __shared__ float srow[4][HDIM];
    int wid = blockIdx.x * 4 + w, nw = gridDim.x * 4;
    for (int n = wid; n < N_NODES; n += nw) {
        srow[w][o] = in[(size_t)n * HDIM + o];
        float acc = bias;
        if (deg) acc = fmaf((float)deg[n], db, acc);
        #pragma unroll
        for (int k4 = 0; k4 < HDIM / 4; ++k4) {
            float4 c = *reinterpret_cast<const float4*>(&srow[w][k4 * 4]);
            acc = fmaf(c.x, Wc[4 * k4 + 0], acc);
            acc = fmaf(c.y, Wc[4 * k4 + 1], acc);
            acc = fmaf(c.z, Wc[4 * k4 + 2], acc);
            acc = fmaf(c.w, Wc[4 * k4 + 3], acc);
        }
        if (relu) acc = fmaxf(acc, 0.f);
        if (out) out[(size_t)n * HDIM + o] = acc;
        else     outH[(size_t)n * HDIM + o] = __float2half(acc);
    }
}

// out = relu(in1 @ W1 + in2 @ W2 + b)
__global__ void lin64_dual_kernel(const float* __restrict__ in1, const float* __restrict__ W1,
                                  const float* __restrict__ in2, const float* __restrict__ W2,
                                  const float* __restrict__ b, float* __restrict__ out)
{
    int o = threadIdx.x & 63;
    int w = threadIdx.x >> 6;
    float Wc1[HDIM], Wc2[HDIM];
    #pragma unroll
    for (int k = 0; k < HDIM; ++k) Wc1[k] = W1[k * HDIM + o];
    #pragma unroll
    for (int k = 0; k < HDIM; ++k) Wc2[k] = W2[k * HDIM + o];
    float bias = b[o];
    __shared__ float srA[4][HDIM];
    __shared__ float srB[4][HDIM];
    int wid = blockIdx.x * 4 + w, nw = gridDim.x * 4;
    for (int n = wid; n < N_NODES; n += nw) {
        srA[w][o] = in1[(size_t)n * HDIM + o];
        srB[w][o] = in2[(size_t)n * HDIM + o];
        float acc = bias;
        #pragma unroll
        for (int k4 = 0; k4 < HDIM / 4; ++k4) {
            float4 c = *reinterpret_cast<const float4*>(&srA[w][k4 * 4]);
            acc = fmaf(c.x, Wc1[4 * k4 + 0], acc);
            acc = fmaf(c.y, Wc1[4 * k4 + 1], acc);
            acc = fmaf(c.z, Wc1[4 * k4 + 2], acc);
            acc = fmaf(c.w, Wc1[4 * k4 + 3], acc);
        }
        #pragma unroll
        for (int k4 = 0; k4 < HDIM / 4; ++k4) {
            float4 c = *reinterpret_cast<const float4*>(&srB[w][k4 * 4]);
            acc = fmaf(c.x, Wc2[4 * k4 + 0], acc);
            acc = fmaf(c.y, Wc2[4 * k4 + 1], acc);
            acc = fmaf(c.z, Wc2[4 * k4 + 2], acc);
            acc = fmaf(c.w, Wc2[4 * k4 + 3], acc);
        }
        out[(size_t)n * HDIM + o] = fmaxf(acc, 0.f);
    }
}

// ---------------- edge aggregation (CSR gather, fp16 data, no atomics) ----------------
__device__ __forceinline__ float edge_term(float hv, uint4 a, uint4 b,
                                           const float* Kc, float kbo)
{
    float z = hv + kbo;
    float2 t;
    t = h2f2(a.x); z = fmaf(t.x, Kc[0], z);  z = fmaf(t.y, Kc[1], z);
    t = h2f2(a.y); z = fmaf(t.x, Kc[2], z);  z = fmaf(t.y, Kc[3], z);
    t = h2f2(a.z); z = fmaf(t.x, Kc[4], z);  z = fmaf(t.y, Kc[5], z);
    t = h2f2(a.w); z = fmaf(t.x, Kc[6], z);  z = fmaf(t.y, Kc[7], z);
    t = h2f2(b.x); z = fmaf(t.x, Kc[8], z);  z = fmaf(t.y, Kc[9], z);
    t = h2f2(b.y); z = fmaf(t.x, Kc[10], z); z = fmaf(t.y, Kc[11], z);
    t = h2f2(b.z); z = fmaf(t.x, Kc[12], z); z = fmaf(t.y, Kc[13], z);
    t = h2f2(b.w); z = fmaf(t.x, Kc[14], z); z = fmaf(t.y, Kc[15], z);
    return fmaxf(z, 0.f);
}

__global__ void edge_agg_kernel(const int* __restrict__ rowptr, const int* __restrict__ srcIdx,
                                const uint4* __restrict__ eaPh, const __half* __restrict__ hWh,
                                const float* __restrict__ K, const float* __restrict__ kb,
                                float* __restrict__ aggZ)
{
    int o = threadIdx.x & 63;
    int w = threadIdx.x >> 6;
    float Kc[EDGE_C];
    #pragma unroll
    for (int k = 0; k < EDGE_C; ++k) Kc[k] = K[k * HDIM + o];
    float kbo = kb[o];
    int wid = blockIdx.x * 4 + w, nw = gridDim.x * 4;
    for (int n = wid; n < N_NODES; n += nw) {
        int beg = __builtin_amdgcn_readfirstlane(rowptr[n]);
        int end = __builtin_amdgcn_readfirstlane(rowptr[n + 1]);
        float acc = 0.f;
        int p = beg;
        for (; p + 3 < end; p += 4) {
            int s0 = srcIdx[p], s1 = srcIdx[p + 1], s2 = srcIdx[p + 2], s3 = srcIdx[p + 3];
            uint4 a0 = eaPh[2 * (size_t)p + 0], b0 = eaPh[2 * (size_t)p + 1];
            uint4 a1 = eaPh[2 * (size_t)p + 2], b1 = eaPh[2 * (size_t)p + 3];
            uint4 a2 = eaPh[2 * (size_t)p + 4], b2 = eaPh[2 * (size_t)p + 5];
            uint4 a3 = eaPh[2 * (size_t)p + 6], b3 = eaPh[2 * (size_t)p + 7];
            float h0 = __half2float(hWh[(size_t)s0 * HDIM + o]);
            float h1 = __half2float(hWh[(size_t)s1 * HDIM + o]);
            float h2 = __half2float(hWh[(size_t)s2 * HDIM + o]);
            float h3 = __half2float(hWh[(size_t)s3 * HDIM + o]);
            acc += edge_term(h0, a0, b0, Kc, kbo);
            acc += edge_term(h1, a1, b1, Kc, kbo);
            acc += edge_term(h2, a2, b2, Kc, kbo);
            acc += edge_term(h3, a3, b3, Kc, kbo);
        }
        for (; p < end; ++p) {
            int s = srcIdx[p];
            uint4 a = eaPh[2 * (size_t)p], b = eaPh[2 * (size_t)p + 1];
            float hv = __half2float(hWh[(size_t)s * HDIM + o]);
            acc += edge_term(hv, a, b, Kc, kbo);
        }
        aggZ[(size_t)n * HDIM + o] = acc;
    }
}

// ---------------- pooling / readout ----------------
__global__ void pool_graph_kernel(const float* __restrict__ h, const int* __restrict__ gptr,
                                  float* __restrict__ pooled)
{
    int o = threadIdx.x & 63;
    int w = threadIdx.x >> 6;
    int wid = blockIdx.x * 4 + w, nw = gridDim.x * 4;
    for (int g = wid; g < N_GRAPH; g += nw) {
        int beg = gptr[g], end = gptr[g + 1];
        float acc = 0.f;
        for (int n = beg; n < end; ++n) acc += h[(size_t)n * HDIM + o];
        pooled[g * HDIM + o] = acc;
    }
}

__global__ void readout_kernel(const float* __restrict__ pooled, const int* __restrict__ gptr,
                               const float* __restrict__ desc,
                               const float* __restrict__ W1, const float* __restrict__ b1,
                               const float* __restrict__ W2, const float* __restrict__ b2,
                               float* __restrict__ out)
{
    __shared__ float r[HDIM + DESC_C];
    __shared__ float red[128];
    int g = blockIdx.x;
    int t = threadIdx.x;
    float c = fmaxf((float)(gptr[g + 1] - gptr[g]), 1.f);
    for (int i = t; i < HDIM; i += 128) r[i] = pooled[g * HDIM + i] / c;
    for (int i = t; i < DESC_C; i += 128) r[HDIM + i] = desc[(size_t)g * DESC_C + i];
    __syncthreads();
    float acc = b1[t];
    for (int k = 0; k < HDIM + DESC_C; ++k) acc = fmaf(r[k], W1[k * 128 + t], acc);
    acc = fmaxf(acc, 0.f) * W2[t];
    red[t] = acc;
    __syncthreads();
    for (int s = 64; s > 0; s >>= 1) {
        if (t < s) red[t] += red[t + s];
        __syncthreads();
    }
    if (t == 0) out[g] = 1.f / (1.f + expf(-(red[0] + b2[0])));
}

extern "C" void kernel_launch(void* const* d_in, const int* in_sizes, int n_in,
                              void* d_out, int out_size, void* d_ws, size_t ws_size,
                              hipStream_t stream)
{
    const float* x         = (const float*)d_in[0];
    const int*   ei        = (const int*)d_in[1];
    const float* edge_attr = (const float*)d_in[2];
    const int*   batch     = (const int*)d_in[3];
    const float* desc      = (const float*)d_in[4];
    const float* node_W    = (const float*)d_in[5];
    const float* node_b    = (const float*)d_in[6];
    const float* edge_W    = (const float*)d_in[7];
    const float* edge_b    = (const float*)d_in[8];
    const float* emW1      = (const float*)d_in[9];
    const float* emb1      = (const float*)d_in[10];
    const float* emW2      = (const float*)d_in[11];
    const float* emb2      = (const float*)d_in[12];
    const float* umW1      = (const float*)d_in[13];
    const float* umb1      = (const float*)d_in[14];
    const float* umW2      = (const float*)d_in[15];
    const float* umb2      = (const float*)d_in[16];
    const float* ro_W1     = (const float*)d_in[17];
    const float* ro_b1     = (const float*)d_in[18];
    const float* ro_W2     = (const float*)d_in[19];
    const float* ro_b2     = (const float*)d_in[20];

    size_t NH = (size_t)N_NODES * HDIM;
    float* bufA   = (float*)d_ws;            // h
    float* bufB   = bufA + NH;               // hW1(as half) / A(fp32)
    float* bufC   = bufB + NH;               // aggZ / t
    uint4* eaPh   = (uint4*)(bufC + NH);     // E*2 uint4 = 51.2 MB, CSR-ordered fp16 edge_attr
    int*   srcIdx = (int*)(eaPh + 2 * (size_t)N_EDGES);
    int*   eIdx   = srcIdx + N_EDGES;
    int*   deg    = eIdx + N_EDGES;
    int*   rowptr = deg + N_NODES;
    int*   cursor = rowptr + N_NODES + 1;
    int*   cnt    = cursor + N_NODES;
    int*   gptr   = cnt + N_GRAPH;
    int*   bsum   = gptr + N_GRAPH + 1;
    int*   bscan  = bsum + N_SBLK;
    float* K3     = (float*)(bscan + N_SBLK + 1);
    float* kb3    = K3 + LAYERS * EDGE_C * HDIM;
    float* pooled = kb3 + LAYERS * HDIM;

    __half* hWh = (__half*)bufB;

    hipMemsetAsync(deg, 0, N_NODES * sizeof(int), stream);
    hipMemsetAsync(cnt, 0, N_GRAPH * sizeof(int), stream);

    precompute_kernel<<<12, 256, 0, stream>>>(edge_W, edge_b, emW1, emb1, K3, kb3);
    lin32_kernel<<<2048, 256, 0, stream>>>(x, node_W, node_b, bufA);
    deg_kernel<<<(N_EDGES + 255) / 256, 256, 0, stream>>>(ei, deg);
    cnt_kernel<<<(N_NODES + 255) / 256, 256, 0, stream>>>(batch, cnt);

    // CSR build
    scanA_kernel<<<N_SBLK, SCAN_B, 0, stream>>>(deg, rowptr, bsum);
    scan1b_kernel<<<1, SCAN_B, 0, stream>>>(bsum, N_SBLK, bscan);
    scanC_kernel<<<N_SBLK, SCAN_B, 0, stream>>>(rowptr, bscan, cursor);
    fill_kernel<<<(N_EDGES + 255) / 256, 256, 0, stream>>>(ei, cursor, srcIdx, eIdx);

    // CSR-ordered fp16 edge_attr + graph ptr
    perm_kernel<<<(N_EDGES + 255) / 256, 256, 0, stream>>>(eIdx, edge_attr, eaPh);
    scan1b_kernel<<<1, SCAN_B, 0, stream>>>(cnt, N_GRAPH, gptr);

    for (int l = 0; l < LAYERS; ++l) {
        const float* W1u = emW1 + l * 2 * HDIM * HDIM;
        // hW1 (fp16) = h @ emW1_upper
        lin64_kernel<<<4096, 256, 0, stream>>>(bufA, W1u, nullptr, nullptr, nullptr, 0,
                                               nullptr, hWh);
        // aggZ = sum_dst relu(hW1[src] + ea@K + kb)
        edge_agg_kernel<<<4096, 256, 0, stream>>>(rowptr, srcIdx, eaPh, hWh,
                                                  K3 + l * EDGE_C * HDIM, kb3 + l * HDIM, bufC);
        // A = aggZ @ emW2 + deg*emb2
        lin64_kernel<<<4096, 256, 0, stream>>>(bufC, emW2 + l * HDIM * HDIM, nullptr,
                                               deg, emb2 + l * HDIM, 0, bufB, nullptr);
        // t = relu(h @ umW1u + A @ umW1l + umb1)
        lin64_dual_kernel<<<4096, 256, 0, stream>>>(bufA, umW1 + l * 2 * HDIM * HDIM,
                                                    bufB, umW1 + l * 2 * HDIM * HDIM + HDIM * HDIM,
                                                    umb1 + l * HDIM, bufC);
        // h = t @ umW2 + umb2
        lin64_kernel<<<4096, 256, 0, stream>>>(bufC, umW2 + l * HDIM * HDIM, umb2 + l * HDIM,
                                               nullptr, nullptr, 0, bufA, nullptr);
    }

    pool_graph_kernel<<<256, 256, 0, stream>>>(bufA, gptr, pooled);
    readout_kernel<<<N_GRAPH, 128, 0, stream>>>(pooled, gptr, desc, ro_W1, ro_b1, ro_W2, ro_b2,
                                                (float*)d_out);
}